// Round 1
// baseline (1543.262 us; speedup 1.0000x reference)
//
#include <hip/hip_runtime.h>

#define NE 32      // experts
#define NK 4       // top-k
#define HD 2048    // hidden
#define ID 1024    // intermediate
#define NT 4096    // tokens
#define TKR (NT*NK) // total routed rows = 16384
#define BM 128
#define BK 64
#define LDA 72     // padded LDS row stride (bf16 elems): 2-way bank aliasing only
#define MAXTILES 160

typedef __attribute__((ext_vector_type(8))) short short8;
typedef __attribute__((ext_vector_type(4))) float floatx4;

__device__ __forceinline__ unsigned short f2bf(float f) {
  // round-to-nearest-even fp32 -> bf16
  unsigned u = __builtin_bit_cast(unsigned, f);
  unsigned r = u + 0x7fffu + ((u >> 16) & 1u);
  return (unsigned short)(r >> 16);
}

// ---------------- x fp32 -> bf16 ----------------
__global__ __launch_bounds__(256) void cvt_kernel(const float* __restrict__ x,
                                                  unsigned short* __restrict__ xb) {
  size_t i = ((size_t)blockIdx.x * 256 + threadIdx.x) * 8;
  if (i >= (size_t)NT * HD) return;
  float4 a = *(const float4*)(x + i);
  float4 b = *(const float4*)(x + i + 4);
  union { unsigned short s[8]; int4 v; } p;
  p.s[0]=f2bf(a.x); p.s[1]=f2bf(a.y); p.s[2]=f2bf(a.z); p.s[3]=f2bf(a.w);
  p.s[4]=f2bf(b.x); p.s[5]=f2bf(b.y); p.s[6]=f2bf(b.z); p.s[7]=f2bf(b.w);
  *(int4*)(xb + i) = p.v;
}

// ---------------- router: logits -> sigmoid -> top4 -> weights ----------------
__global__ __launch_bounds__(256) void router_kernel(
    const float* __restrict__ x, const float* __restrict__ gate_w,
    const float* __restrict__ bias, int* __restrict__ topk_idx,
    float* __restrict__ topk_w, int* __restrict__ counts) {
  int t = blockIdx.x;
  int tid = threadIdx.x;
  int e = tid >> 3, l8 = tid & 7;     // 8 threads per expert
  const float* xr = x + (size_t)t * HD;
  const float* gr = gate_w + (size_t)e * HD;
  float s = 0.f;
  int base = l8 * 256;
#pragma unroll 8
  for (int i = 0; i < 256; i += 4) {
    float4 xv = *(const float4*)(xr + base + i);
    float4 gv = *(const float4*)(gr + base + i);
    s += xv.x*gv.x + xv.y*gv.y + xv.z*gv.z + xv.w*gv.w;
  }
  s += __shfl_down(s, 4, 64);
  s += __shfl_down(s, 2, 64);
  s += __shfl_down(s, 1, 64);
  __shared__ float sc[NE];
  if (l8 == 0) sc[e] = s;
  __syncthreads();
  if (tid == 0) {
    float sig[NE], sel[NE];
    for (int i = 0; i < NE; i++) {
      sig[i] = 1.f / (1.f + expf(-sc[i]));
      sel[i] = sig[i] + bias[i];       // bias affects selection only
    }
    int idxs[NK]; float wsum = 0.f;
    for (int k = 0; k < NK; k++) {
      int bi = 0; float bv = -1e30f;
      for (int i = 0; i < NE; i++)
        if (sel[i] > bv) { bv = sel[i]; bi = i; }   // ties -> lowest index
      sel[bi] = -1e30f;
      idxs[k] = bi; wsum += sig[bi];
    }
    for (int k = 0; k < NK; k++) {
      topk_idx[t*NK + k] = idxs[k];
      topk_w[t*NK + k] = sig[idxs[k]] / wsum;
      atomicAdd(&counts[idxs[k]], 1);
    }
  }
}

// ---------------- plan: offsets + tile descriptors ----------------
__global__ void plan_kernel(const int* __restrict__ counts, int* __restrict__ offsets,
                            int* __restrict__ cursor, int* __restrict__ tiles,
                            int* __restrict__ numtiles) {
  if (threadIdx.x == 0) {
    int off = 0;
    for (int e = 0; e < NE; e++) { offsets[e] = off; off += counts[e]; cursor[e] = 0; }
    offsets[NE] = off;
    int nt = 0;
    for (int e = 0; e < NE; e++) {
      int start = offsets[e], n = counts[e];
      for (int r = 0; r < n; r += BM) {
        tiles[nt*3+0] = e; tiles[nt*3+1] = start + r; tiles[nt*3+2] = min(BM, n - r);
        nt++;
      }
    }
    *numtiles = nt;
  }
}

// ---------------- scatter to expert-sorted order ----------------
__global__ __launch_bounds__(256) void scatter_kernel(
    const int* __restrict__ topk_idx, const float* __restrict__ topk_w,
    const int* __restrict__ offsets, int* __restrict__ cursor,
    int* __restrict__ sorted_token, float* __restrict__ sorted_w) {
  int i = blockIdx.x * 256 + threadIdx.x;   // [0, TKR)
  int e = topk_idx[i];
  int pos = offsets[e] + atomicAdd(&cursor[e], 1);
  sorted_token[pos] = i >> 2;
  sorted_w[pos] = topk_w[i];
}

// ---------------- GEMM1: gu = X_e @ w13_e^T, fused SwiGLU*weight -> h bf16 ----
__global__ __launch_bounds__(256) void gemm1_kernel(
    const unsigned short* __restrict__ xb, const float* __restrict__ w13,
    const int* __restrict__ tiles, const int* __restrict__ numtiles,
    const int* __restrict__ sorted_token, const float* __restrict__ sorted_w,
    unsigned short* __restrict__ hbuf) {
  int mt = blockIdx.y;
  if (mt >= *numtiles) return;
  int e = tiles[mt*3+0], g0 = tiles[mt*3+1], mrows = tiles[mt*3+2];
  int nb = blockIdx.x * 64;   // gate-col base; up cols at +ID

  __shared__ unsigned short As[BM*LDA];
  __shared__ unsigned short Bs[BM*LDA];

  int tid = threadIdx.x;
  int wave = tid >> 6, lane = tid & 63;
  int m15 = lane & 15, q = lane >> 4;
  const float* w13e = w13 + (size_t)e * (2*ID) * HD;

  const unsigned short* aptr[4]; const float* bptr[4]; int sto[4];
#pragma unroll
  for (int i = 0; i < 4; i++) {
    int c = tid + 256*i;
    int r = c >> 3;
    int col = (c & 7) * 8;
    int rr = r < mrows ? r : 0;
    aptr[i] = xb + (size_t)sorted_token[g0+rr] * HD + col;
    int sr = (r < 64) ? (nb + r) : (ID + nb + r - 64);  // gate rows | up rows
    bptr[i] = w13e + (size_t)sr * HD + col;
    sto[i] = r * LDA + col;
  }

  floatx4 acc[2][8];
  floatx4 zf = {0.f,0.f,0.f,0.f};
#pragma unroll
  for (int mi=0;mi<2;mi++)
#pragma unroll
    for (int ni=0;ni<8;ni++) acc[mi][ni] = zf;

  for (int k0 = 0; k0 < HD; k0 += BK) {
    int4 av[4]; float4 b0[4], b1[4];
#pragma unroll
    for (int i = 0; i < 4; i++) {
      av[i] = *(const int4*)(aptr[i] + k0);
      b0[i] = *(const float4*)(bptr[i] + k0);
      b1[i] = *(const float4*)(bptr[i] + k0 + 4);
    }
#pragma unroll
    for (int i = 0; i < 4; i++) {
      *(int4*)(&As[sto[i]]) = av[i];
      union { unsigned short s[8]; int4 v; } p;
      p.s[0]=f2bf(b0[i].x); p.s[1]=f2bf(b0[i].y); p.s[2]=f2bf(b0[i].z); p.s[3]=f2bf(b0[i].w);
      p.s[4]=f2bf(b1[i].x); p.s[5]=f2bf(b1[i].y); p.s[6]=f2bf(b1[i].z); p.s[7]=f2bf(b1[i].w);
      *(int4*)(&Bs[sto[i]]) = p.v;
    }
    __syncthreads();
#pragma unroll
    for (int ks = 0; ks < 2; ks++) {
      int ko = ks*32 + q*8;
      short8 af[2], bfr[8];
#pragma unroll
      for (int mi = 0; mi < 2; mi++)
        af[mi] = *(const short8*)(&As[(wave*32 + 16*mi + m15)*LDA + ko]);
#pragma unroll
      for (int ni = 0; ni < 8; ni++)
        bfr[ni] = *(const short8*)(&Bs[(16*ni + m15)*LDA + ko]);
#pragma unroll
      for (int mi = 0; mi < 2; mi++)
#pragma unroll
        for (int ni = 0; ni < 8; ni++)
          acc[mi][ni] = __builtin_amdgcn_mfma_f32_16x16x32_bf16(af[mi], bfr[ni], acc[mi][ni], 0, 0, 0);
    }
    __syncthreads();
  }
  // epilogue: h = silu(gate)*up * combine_weight (gate=ni 0..3, up=ni 4..7 same lane)
#pragma unroll
  for (int mi = 0; mi < 2; mi++)
#pragma unroll
    for (int r = 0; r < 4; r++) {
      int row = wave*32 + 16*mi + q*4 + r;
      if (row < mrows) {
        int g = g0 + row;
        float wr = sorted_w[g];
        unsigned short* hr = hbuf + (size_t)g * ID + nb;
#pragma unroll
        for (int ni = 0; ni < 4; ni++) {
          float gv = acc[mi][ni][r];
          float uv = acc[mi][ni+4][r];
          float sg = gv / (1.f + __expf(-gv));
          hr[16*ni + m15] = f2bf(sg * uv * wr);
        }
      }
    }
}

// ---------------- GEMM2: out[tok] += h_e @ w2_e^T ----------------
__global__ __launch_bounds__(256) void gemm2_kernel(
    const unsigned short* __restrict__ hbuf, const float* __restrict__ w2,
    const int* __restrict__ tiles, const int* __restrict__ numtiles,
    const int* __restrict__ sorted_token, float* __restrict__ out) {
  int mt = blockIdx.y;
  if (mt >= *numtiles) return;
  int e = tiles[mt*3+0], g0 = tiles[mt*3+1], mrows = tiles[mt*3+2];
  int nb = blockIdx.x * BM;   // 128 cols of H

  __shared__ unsigned short As[BM*LDA];
  __shared__ unsigned short Bs[BM*LDA];

  int tid = threadIdx.x;
  int wave = tid >> 6, lane = tid & 63;
  int m15 = lane & 15, q = lane >> 4;
  const float* w2e = w2 + (size_t)e * HD * ID;

  const unsigned short* aptr[4]; const float* bptr[4]; int sto[4];
#pragma unroll
  for (int i = 0; i < 4; i++) {
    int c = tid + 256*i;
    int r = c >> 3;
    int col = (c & 7) * 8;
    int rr = r < mrows ? r : 0;
    aptr[i] = hbuf + (size_t)(g0 + rr) * ID + col;
    bptr[i] = w2e + (size_t)(nb + r) * ID + col;
    sto[i] = r * LDA + col;
  }

  floatx4 acc[2][8];
  floatx4 zf = {0.f,0.f,0.f,0.f};
#pragma unroll
  for (int mi=0;mi<2;mi++)
#pragma unroll
    for (int ni=0;ni<8;ni++) acc[mi][ni] = zf;

  for (int k0 = 0; k0 < ID; k0 += BK) {
    int4 av[4]; float4 b0[4], b1[4];
#pragma unroll
    for (int i = 0; i < 4; i++) {
      av[i] = *(const int4*)(aptr[i] + k0);
      b0[i] = *(const float4*)(bptr[i] + k0);
      b1[i] = *(const float4*)(bptr[i] + k0 + 4);
    }
#pragma unroll
    for (int i = 0; i < 4; i++) {
      *(int4*)(&As[sto[i]]) = av[i];
      union { unsigned short s[8]; int4 v; } p;
      p.s[0]=f2bf(b0[i].x); p.s[1]=f2bf(b0[i].y); p.s[2]=f2bf(b0[i].z); p.s[3]=f2bf(b0[i].w);
      p.s[4]=f2bf(b1[i].x); p.s[5]=f2bf(b1[i].y); p.s[6]=f2bf(b1[i].z); p.s[7]=f2bf(b1[i].w);
      *(int4*)(&Bs[sto[i]]) = p.v;
    }
    __syncthreads();
#pragma unroll
    for (int ks = 0; ks < 2; ks++) {
      int ko = ks*32 + q*8;
      short8 af[2], bfr[8];
#pragma unroll
      for (int mi = 0; mi < 2; mi++)
        af[mi] = *(const short8*)(&As[(wave*32 + 16*mi + m15)*LDA + ko]);
#pragma unroll
      for (int ni = 0; ni < 8; ni++)
        bfr[ni] = *(const short8*)(&Bs[(16*ni + m15)*LDA + ko]);
#pragma unroll
      for (int mi = 0; mi < 2; mi++)
#pragma unroll
        for (int ni = 0; ni < 8; ni++)
          acc[mi][ni] = __builtin_amdgcn_mfma_f32_16x16x32_bf16(af[mi], bfr[ni], acc[mi][ni], 0, 0, 0);
    }
    __syncthreads();
  }
  // epilogue: atomic combine (h already weight-scaled)
#pragma unroll
  for (int mi = 0; mi < 2; mi++)
#pragma unroll
    for (int r = 0; r < 4; r++) {
      int row = wave*32 + 16*mi + q*4 + r;
      if (row < mrows) {
        int tok = sorted_token[g0 + row];
        float* orow = out + (size_t)tok * HD + nb;
#pragma unroll
        for (int ni = 0; ni < 8; ni++)
          atomicAdd(&orow[16*ni + m15], acc[mi][ni][r]);
      }
    }
}

// ---------------- workspace layout (bytes) ----------------
#define WS_COUNTS   0u
#define WS_CURSOR   128u
#define WS_OFFSETS  256u
#define WS_NUMTILES 512u
#define WS_TILES    1024u
#define WS_TOPKI    4096u
#define WS_TOPKW    (WS_TOPKI + TKR*4u)     // 69632
#define WS_SORTTOK  (WS_TOPKW + TKR*4u)     // 135168
#define WS_SORTW    (WS_SORTTOK + TKR*4u)   // 200704
#define WS_XB       (WS_SORTW + TKR*4u)     // 266240
#define WS_HBUF     (WS_XB + (size_t)NT*HD*2u)
// total = WS_HBUF + TKR*ID*2 = ~50.6 MB

extern "C" void kernel_launch(void* const* d_in, const int* in_sizes, int n_in,
                              void* d_out, int out_size, void* d_ws, size_t ws_size,
                              hipStream_t stream) {
  const float* x      = (const float*)d_in[0];
  const float* gate_w = (const float*)d_in[1];
  const float* bias   = (const float*)d_in[2];
  const float* w13    = (const float*)d_in[3];
  const float* w2     = (const float*)d_in[4];
  float* out = (float*)d_out;

  char* ws = (char*)d_ws;
  int*   counts   = (int*)(ws + WS_COUNTS);
  int*   cursor   = (int*)(ws + WS_CURSOR);
  int*   offsets  = (int*)(ws + WS_OFFSETS);
  int*   numtiles = (int*)(ws + WS_NUMTILES);
  int*   tiles    = (int*)(ws + WS_TILES);
  int*   topk_idx = (int*)(ws + WS_TOPKI);
  float* topk_w   = (float*)(ws + WS_TOPKW);
  int*   sorted_token = (int*)(ws + WS_SORTTOK);
  float* sorted_w     = (float*)(ws + WS_SORTW);
  unsigned short* xb   = (unsigned short*)(ws + WS_XB);
  unsigned short* hbuf = (unsigned short*)(ws + WS_HBUF);

  hipMemsetAsync(ws, 0, 1024, stream);                         // counts/cursor
  hipMemsetAsync(d_out, 0, (size_t)out_size * 4, stream);      // combine target

  cvt_kernel<<<NT*HD/8/256, 256, 0, stream>>>(x, xb);
  router_kernel<<<NT, 256, 0, stream>>>(x, gate_w, bias, topk_idx, topk_w, counts);
  plan_kernel<<<1, 64, 0, stream>>>(counts, offsets, cursor, tiles, numtiles);
  scatter_kernel<<<TKR/256, 256, 0, stream>>>(topk_idx, topk_w, offsets, cursor,
                                              sorted_token, sorted_w);
  gemm1_kernel<<<dim3(2*ID/BM, MAXTILES), 256, 0, stream>>>(xb, w13, tiles, numtiles,
                                                            sorted_token, sorted_w, hbuf);
  gemm2_kernel<<<dim3(HD/BM, MAXTILES), 256, 0, stream>>>(hbuf, w2, tiles, numtiles,
                                                          sorted_token, out);
}